// Round 2
// baseline (1342.765 us; speedup 1.0000x reference)
//
#include <hip/hip_runtime.h>

#define HW   256
#define HW2  (HW * HW)
#define CIN  64
#define COUT 64

// ---------------------------------------------------------------------------
// Kernel A: offset conv  off[b,m,r,c] = pb[m] + sum_{ic,dr,dc} pw[m,ic,dr,dc]
//                                        * x[b,ic,r-1+dr,c-1+dc]   (zero pad)
// m split 3-way over blockIdx.z (6 channels each) for occupancy.
// Block = 4 rows x 64 cols (lanes along c -> coalesced loads/stores).
// ---------------------------------------------------------------------------
__global__ __launch_bounds__(256, 4) void offs_kernel(
    const float* __restrict__ x, const float* __restrict__ pw,
    const float* __restrict__ pb, float* __restrict__ off)
{
  const int b  = blockIdx.y;
  const int mb = blockIdx.z * 6;             // 0, 6, 12
  const int bx = blockIdx.x;                 // 64 row-tiles * 4 col-tiles
  const int r = (bx >> 2) * 4 + (threadIdx.x >> 6);
  const int c = (bx & 3) * 64 + (threadIdx.x & 63);

  float acc[6];
#pragma unroll
  for (int m = 0; m < 6; ++m) acc[m] = pb[mb + m];

  const float* xb = x + (size_t)b * CIN * HW2;
  for (int ic = 0; ic < CIN; ++ic) {
    const float* xc = xb + ic * HW2;
    float v[9];
#pragma unroll
    for (int dr = 0; dr < 3; ++dr) {
      const int rr = r - 1 + dr;
#pragma unroll
      for (int dc = 0; dc < 3; ++dc) {
        const int cc = c - 1 + dc;
        const bool ok = (rr >= 0) & (rr < HW) & (cc >= 0) & (cc < HW);
        v[dr * 3 + dc] = ok ? xc[rr * HW + cc] : 0.f;
      }
    }
#pragma unroll
    for (int m = 0; m < 6; ++m) {
      const float* wp = pw + (((mb + m) * CIN) + ic) * 9;   // uniform -> s_load
      float a = acc[m];
#pragma unroll
      for (int k = 0; k < 9; ++k) a = fmaf(wp[k], v[k], a);
      acc[m] = a;
    }
  }
#pragma unroll
  for (int m = 0; m < 6; ++m)
    off[(((size_t)b * 18 + mb + m) * HW + r) * HW + c] = acc[m];
}

// ---------------------------------------------------------------------------
// Kernel B: fused bilinear sampling + contraction, oc split 2-way over
// blockIdx.z (acc[32]). Corner indices packed 2-per-u32 (idx <= 65535) so
// live state ~ 32 acc + 18 packed idx + 36 fp32 weights < 128 VGPR (no spill).
// Reference quirk (np.meshgrid 'xy'): at output (r,c) the sample base is
// (row = c+1, col = r+1). Lanes run along r so gather columns (~r) coalesce.
// ---------------------------------------------------------------------------
__global__ __launch_bounds__(256, 4) void deform_kernel(
    const float* __restrict__ x, const float* __restrict__ off,
    const float* __restrict__ w, float* __restrict__ out)
{
  const int b  = blockIdx.y;
  const int ob0 = blockIdx.z * 32;           // oc half
  const int bx = blockIdx.x;                 // 4 row-tiles * 64 col-tiles
  const int r = (bx & 3) * 64 + (threadIdx.x & 63);   // lanes along r
  const int c = (bx >> 2) * 4 + (threadIdx.x >> 6);

  unsigned qip[9][2];                        // packed corner idx (16b each)
  float    qg[9][4];
  const float* obp = off + (size_t)b * 18 * HW2;
#pragma unroll
  for (int n = 0; n < 9; ++n) {
    const float ox = obp[(n * HW + r) * HW + c];
    const float oy = obp[((9 + n) * HW + r) * HW + c];
    // p = p0 + pn + off;  p0x = c+1 (transposed base!), pnx = n%3-1
    const float px = (float)(c + (n % 3)) + ox;      // row coord into padded
    const float py = (float)(r + (n / 3)) + oy;      // col coord into padded
    const float fx = floorf(px);
    const float fy = floorf(py);
    int ltx = (int)fx, lty = (int)fy;
    int rbx = ltx + 1, rby = lty + 1;
    ltx = min(max(ltx, 0), HW + 1); lty = min(max(lty, 0), HW + 1);
    rbx = min(max(rbx, 0), HW + 1); rby = min(max(rby, 0), HW + 1);
    const float pxc = fminf(fmaxf(px, 0.f), (float)(HW + 1));
    const float pyc = fminf(fmaxf(py, 0.f), (float)(HW + 1));
    const float wxl = 1.f + (float)ltx - pxc;        // (1+dx_lt)
    const float wxr = 1.f - ((float)rbx - pxc);      // (1-dx_rb)
    const float wyl = 1.f + (float)lty - pyc;        // (1+dy_lt)
    const float wyr = 1.f - ((float)rby - pyc);      // (1-dy_rb)
    const int   cx[4] = { ltx, rbx, ltx, rbx };
    const int   cy[4] = { lty, rby, rby, lty };
    const float cg[4] = { wxl * wyl, wxr * wyr, wxl * wyr, wxr * wyl };
    unsigned ii[4];
#pragma unroll
    for (int k = 0; k < 4; ++k) {
      // padded image: border ring is zeros -> weight 0, idx into UNPADDED x
      const bool ok = (cx[k] >= 1) & (cx[k] <= HW) & (cy[k] >= 1) & (cy[k] <= HW);
      ii[k]    = ok ? (unsigned)((cx[k] - 1) * HW + (cy[k] - 1)) : 0u;
      qg[n][k] = ok ? cg[k] : 0.f;
    }
    qip[n][0] = ii[0] | (ii[1] << 16);
    qip[n][1] = ii[2] | (ii[3] << 16);
  }

  float acc[32];
#pragma unroll
  for (int o = 0; o < 32; ++o) acc[o] = 0.f;

  const float* xb = x + (size_t)b * CIN * HW2;
  for (int ic = 0; ic < CIN; ++ic) {
    const float* xc = xb + ic * HW2;
    float s[9];
#pragma unroll
    for (int n = 0; n < 9; ++n) {
      const unsigned p0 = qip[n][0], p1 = qip[n][1];
      const unsigned i0 = p0 & 0xFFFFu, i1 = p0 >> 16;
      const unsigned i2 = p1 & 0xFFFFu, i3 = p1 >> 16;
      s[n] = qg[n][0] * xc[i0] + qg[n][1] * xc[i1]
           + qg[n][2] * xc[i2] + qg[n][3] * xc[i3];
    }
#pragma unroll
    for (int o = 0; o < 32; ++o) {
      const float* wp = w + (((ob0 + o) * CIN) + ic) * 9;   // uniform -> s_load
      float a = acc[o];
#pragma unroll
      for (int n = 0; n < 9; ++n) a = fmaf(wp[n], s[n], a);
      acc[o] = a;
    }
  }

  float* outb = out + (size_t)b * COUT * HW2;
#pragma unroll
  for (int o = 0; o < 32; ++o)
    outb[((size_t)(ob0 + o) * HW + r) * HW + c] = acc[o];
}

// ---------------------------------------------------------------------------
extern "C" void kernel_launch(void* const* d_in, const int* in_sizes, int n_in,
                              void* d_out, int out_size, void* d_ws, size_t ws_size,
                              hipStream_t stream) {
  const float* x  = (const float*)d_in[0];   // (2,64,256,256)
  const float* pw = (const float*)d_in[1];   // (18,64,3,3)
  const float* pb = (const float*)d_in[2];   // (18,)
  const float* w  = (const float*)d_in[3];   // (64,64,3,3)
  float* out = (float*)d_out;                // (2,64,256,256)
  float* off = (float*)d_ws;                 // needs 2*18*256*256*4 = 9.44 MB

  dim3 gridA(256, 2, 3);
  offs_kernel<<<gridA, 256, 0, stream>>>(x, pw, pb, off);
  dim3 gridB(256, 2, 2);
  deform_kernel<<<gridB, 256, 0, stream>>>(x, off, w, out);
}

// Round 3
// 339.859 us; speedup vs baseline: 3.9509x; 3.9509x over previous
//
#include <hip/hip_runtime.h>

#define HW   256
#define HW2  (HW * HW)
#define CIN  64
#define COUT 64

typedef __attribute__((ext_vector_type(8))) short short8v;   // 8 bf16 = 4 VGPR
typedef __attribute__((ext_vector_type(4))) float f32x4;

__device__ __forceinline__ unsigned short f2bf(float f) {    // RNE fp32->bf16
  unsigned u = __float_as_uint(f);
  u = u + 0x7FFFu + ((u >> 16) & 1u);
  return (unsigned short)(u >> 16);
}

// ---------------------------------------------------------------------------
// Kernel W: pre-swizzle conv weights into MFMA A-fragment order (bf16).
// wf[((icb*9 + n)*4 + t)*64 + lane][e] = bf16( w[oc=16t+(lane&15)]
//                                              [ic=icb*32+8*(lane>>4)+e][n] )
// K-order: k2 = icb*288 + n*32 + (ic&31), matching the sampling side.
// ---------------------------------------------------------------------------
__global__ void wfrag_kernel(const float* __restrict__ w, short* __restrict__ wf) {
  const int T = blockIdx.x * 256 + threadIdx.x;      // 4608 fragments
  if (T >= 4608) return;
  const int l   = T & 63;
  const int t   = (T >> 6) & 3;
  const int g   = T >> 8;                            // icb*9 + n
  const int n   = g % 9;
  const int icb = g / 9;
  const int oc  = t * 16 + (l & 15);
  const int ic0 = icb * 32 + (l >> 4) * 8;
  short8v v;
#pragma unroll
  for (int e = 0; e < 8; ++e)
    v[e] = (short)f2bf(w[(oc * CIN + ic0 + e) * 9 + n]);
  *(short8v*)(wf + (size_t)T * 8) = v;
}

// ---------------------------------------------------------------------------
// Kernel A: offset conv (fp32 VALU, validated in R0/R1). Lanes along c.
// ---------------------------------------------------------------------------
__global__ __launch_bounds__(256, 4) void offs_kernel(
    const float* __restrict__ x, const float* __restrict__ pw,
    const float* __restrict__ pb, float* __restrict__ off)
{
  const int b  = blockIdx.y;
  const int mb = blockIdx.z * 6;             // 0, 6, 12
  const int bx = blockIdx.x;
  const int r = (bx >> 2) * 4 + (threadIdx.x >> 6);
  const int c = (bx & 3) * 64 + (threadIdx.x & 63);

  float acc[6];
#pragma unroll
  for (int m = 0; m < 6; ++m) acc[m] = pb[mb + m];

  const float* xb = x + (size_t)b * CIN * HW2;
  for (int ic = 0; ic < CIN; ++ic) {
    const float* xc = xb + ic * HW2;
    float v[9];
#pragma unroll
    for (int dr = 0; dr < 3; ++dr) {
      const int rr = r - 1 + dr;
#pragma unroll
      for (int dc = 0; dc < 3; ++dc) {
        const int cc = c - 1 + dc;
        const bool ok = (rr >= 0) & (rr < HW) & (cc >= 0) & (cc < HW);
        v[dr * 3 + dc] = ok ? xc[rr * HW + cc] : 0.f;
      }
    }
#pragma unroll
    for (int m = 0; m < 6; ++m) {
      const float* wp = pw + (((mb + m) * CIN) + ic) * 9;   // uniform -> s_load
      float a = acc[m];
#pragma unroll
      for (int k = 0; k < 9; ++k) a = fmaf(wp[k], v[k], a);
      acc[m] = a;
    }
  }
#pragma unroll
  for (int m = 0; m < 6; ++m)
    off[(((size_t)b * 18 + mb + m) * HW + r) * HW + c] = acc[m];
}

// ---------------------------------------------------------------------------
// Kernel B: fused bilinear sampling -> bf16 MFMA contraction. LDS-free.
// Wave w owns pixels (rows) r0+16w .. r0+16w+15 at fixed column c0.
// Thread (i = tid&15, a = (tid>>4)&3): pixel 16w+i, ic-slice a.
// Per K-step (tap n, 32 ics): 8 samples -> B-fragment in registers;
// A-fragments loaded coalesced from pre-swizzled wf; 4 MFMAs (64 oc).
// C/D layout (m89): col = lane&15 = pixel, row(oc) = 16t + 4a + reg.
// ---------------------------------------------------------------------------
__global__ __launch_bounds__(256) void deform_kernel(
    const float* __restrict__ x, const float* __restrict__ off,
    const short* __restrict__ wf, float* __restrict__ out)
{
  const int b   = blockIdx.y;
  const int bx  = blockIdx.x;                 // 4 r-tiles * 256 cols
  const int r0  = (bx & 3) * 64;
  const int c0  = bx >> 2;
  const int tid = threadIdx.x;
  const int lane = tid & 63;
  const int w    = tid >> 6;
  const int i    = tid & 15;
  const int a    = (tid >> 4) & 3;
  const int r = r0 + w * 16 + i;
  const int c = c0;

  // ---- fp32-exact corner tables (validated R1 code, 54 VGPRs) ----
  unsigned qip[9][2];
  float    qg[9][4];
  const float* obp = off + (size_t)b * 18 * HW2;
#pragma unroll
  for (int n = 0; n < 9; ++n) {
    const float ox = obp[(n * HW + r) * HW + c];
    const float oy = obp[((9 + n) * HW + r) * HW + c];
    // p = p0 + pn + off; transposed base: row coord ~ c, col coord ~ r
    const float px = (float)(c + (n % 3)) + ox;
    const float py = (float)(r + (n / 3)) + oy;
    const float fx = floorf(px);
    const float fy = floorf(py);
    int ltx = (int)fx, lty = (int)fy;
    int rbx = ltx + 1, rby = lty + 1;
    ltx = min(max(ltx, 0), HW + 1); lty = min(max(lty, 0), HW + 1);
    rbx = min(max(rbx, 0), HW + 1); rby = min(max(rby, 0), HW + 1);
    const float pxc = fminf(fmaxf(px, 0.f), (float)(HW + 1));
    const float pyc = fminf(fmaxf(py, 0.f), (float)(HW + 1));
    const float wxl = 1.f + (float)ltx - pxc;
    const float wxr = 1.f - ((float)rbx - pxc);
    const float wyl = 1.f + (float)lty - pyc;
    const float wyr = 1.f - ((float)rby - pyc);
    const int   cx[4] = { ltx, rbx, ltx, rbx };
    const int   cy[4] = { lty, rby, rby, lty };
    const float cg[4] = { wxl * wyl, wxr * wyr, wxl * wyr, wxr * wyl };
    unsigned ii[4];
#pragma unroll
    for (int k = 0; k < 4; ++k) {
      const bool ok = (cx[k] >= 1) & (cx[k] <= HW) & (cy[k] >= 1) & (cy[k] <= HW);
      ii[k]    = ok ? (unsigned)((cx[k] - 1) * HW + (cy[k] - 1)) : 0u;
      qg[n][k] = ok ? cg[k] : 0.f;
    }
    qip[n][0] = ii[0] | (ii[1] << 16);
    qip[n][1] = ii[2] | (ii[3] << 16);
  }

  f32x4 acc[4];
#pragma unroll
  for (int t = 0; t < 4; ++t) acc[t] = (f32x4){0.f, 0.f, 0.f, 0.f};

  const float* xb = x + (size_t)b * CIN * HW2;
  for (int icb = 0; icb < 2; ++icb) {
    const char* xbase = (const char*)(xb + (size_t)(icb * 32 + a * 8) * HW2);
    const short* wfb0 = wf + ((size_t)(icb * 9) * 4 * 64 + lane) * 8;
#pragma unroll
    for (int n = 0; n < 9; ++n) {
      const unsigned p0 = qip[n][0], p1 = qip[n][1];
      const int o0 = (int)(p0 & 0xFFFFu) * 4;
      const int o1 = (int)(p0 >> 16) * 4;
      const int o2 = (int)(p1 & 0xFFFFu) * 4;
      const int o3 = (int)(p1 >> 16) * 4;
      const float g0 = qg[n][0], g1 = qg[n][1], g2 = qg[n][2], g3 = qg[n][3];
      short8v bfr;
#pragma unroll
      for (int j = 0; j < 8; ++j) {
        const char* xj = xbase + (size_t)j * (HW2 * 4);
        const float sv = g0 * *(const float*)(xj + o0)
                       + g1 * *(const float*)(xj + o1)
                       + g2 * *(const float*)(xj + o2)
                       + g3 * *(const float*)(xj + o3);
        bfr[j] = (short)f2bf(sv);
      }
      const short* wfb = wfb0 + (size_t)n * 4 * 64 * 8;
#pragma unroll
      for (int t = 0; t < 4; ++t) {
        const short8v afr = *(const short8v*)(wfb + (size_t)t * 64 * 8);
        acc[t] = __builtin_amdgcn_mfma_f32_16x16x32_bf16(afr, bfr, acc[t], 0, 0, 0);
      }
    }
  }

#pragma unroll
  for (int t = 0; t < 4; ++t)
#pragma unroll
    for (int j = 0; j < 4; ++j) {
      const int oc = t * 16 + a * 4 + j;
      out[((size_t)(b * COUT + oc)) * HW2 + (size_t)r * HW + c0] = acc[t][j];
    }
}

// ---------------------------------------------------------------------------
extern "C" void kernel_launch(void* const* d_in, const int* in_sizes, int n_in,
                              void* d_out, int out_size, void* d_ws, size_t ws_size,
                              hipStream_t stream) {
  const float* x  = (const float*)d_in[0];   // (2,64,256,256)
  const float* pw = (const float*)d_in[1];   // (18,64,3,3)
  const float* pb = (const float*)d_in[2];   // (18,)
  const float* w  = (const float*)d_in[3];   // (64,64,3,3)
  float* out = (float*)d_out;                // (2,64,256,256)

  float* off = (float*)d_ws;                                   // 9,437,184 B
  short* wfg = (short*)((char*)d_ws + (size_t)2 * 18 * HW2 * 4); // +73,728 B

  wfrag_kernel<<<18, 256, 0, stream>>>(w, wfg);
  dim3 gridA(256, 2, 3);
  offs_kernel<<<gridA, 256, 0, stream>>>(x, pw, pb, off);
  dim3 gridB(1024, 2);
  deform_kernel<<<gridB, 256, 0, stream>>>(x, off, wfg, out);
}

// Round 4
// 319.879 us; speedup vs baseline: 4.1977x; 1.0625x over previous
//
#include <hip/hip_runtime.h>

#define HW   256
#define HW2  (HW * HW)
#define CIN  64
#define COUT 64

typedef __attribute__((ext_vector_type(8))) short short8v;   // 8 bf16 = 4 VGPR
typedef __attribute__((ext_vector_type(4))) float f32x4;

__device__ __forceinline__ unsigned short f2bf(float f) {    // RNE fp32->bf16
  unsigned u = __float_as_uint(f);
  u = u + 0x7FFFu + ((u >> 16) & 1u);
  return (unsigned short)(u >> 16);
}

// ---------------------------------------------------------------------------
// Kernel W: pre-swizzle conv weights into MFMA A-fragment order (bf16).
// wf[((icb*9 + n)*4 + t)*64 + lane][e] = bf16( w[oc=16t+(lane&15)]
//                                              [ic=icb*32+8*(lane>>4)+e][n] )
// (verified in R2)
// ---------------------------------------------------------------------------
__global__ void wfrag_kernel(const float* __restrict__ w, short* __restrict__ wf) {
  const int T = blockIdx.x * 256 + threadIdx.x;      // 4608 fragments
  if (T >= 4608) return;
  const int l   = T & 63;
  const int t   = (T >> 6) & 3;
  const int g   = T >> 8;                            // icb*9 + n
  const int n   = g % 9;
  const int icb = g / 9;
  const int oc  = t * 16 + (l & 15);
  const int ic0 = icb * 32 + (l >> 4) * 8;
  short8v v;
#pragma unroll
  for (int e = 0; e < 8; ++e)
    v[e] = (short)f2bf(w[(oc * CIN + ic0 + e) * 9 + n]);
  *(short8v*)(wf + (size_t)T * 8) = v;
}

// ---------------------------------------------------------------------------
// Kernel A: offset conv (compute identical to R0-verified). NEW store layout
// off[b][c][ch][r] so deform's per-pixel offset reads coalesce along r.
// ---------------------------------------------------------------------------
__global__ __launch_bounds__(256, 4) void offs_kernel(
    const float* __restrict__ x, const float* __restrict__ pw,
    const float* __restrict__ pb, float* __restrict__ off)
{
  const int b  = blockIdx.y;
  const int mb = blockIdx.z * 6;             // 0, 6, 12
  const int bx = blockIdx.x;
  const int r = (bx >> 2) * 4 + (threadIdx.x >> 6);
  const int c = (bx & 3) * 64 + (threadIdx.x & 63);

  float acc[6];
#pragma unroll
  for (int m = 0; m < 6; ++m) acc[m] = pb[mb + m];

  const float* xb = x + (size_t)b * CIN * HW2;
  for (int ic = 0; ic < CIN; ++ic) {
    const float* xc = xb + ic * HW2;
    float v[9];
#pragma unroll
    for (int dr = 0; dr < 3; ++dr) {
      const int rr = r - 1 + dr;
#pragma unroll
      for (int dc = 0; dc < 3; ++dc) {
        const int cc = c - 1 + dc;
        const bool ok = (rr >= 0) & (rr < HW) & (cc >= 0) & (cc < HW);
        v[dr * 3 + dc] = ok ? xc[rr * HW + cc] : 0.f;
      }
    }
#pragma unroll
    for (int m = 0; m < 6; ++m) {
      const float* wp = pw + (((mb + m) * CIN) + ic) * 9;   // uniform -> s_load
      float a = acc[m];
#pragma unroll
      for (int k = 0; k < 9; ++k) a = fmaf(wp[k], v[k], a);
      acc[m] = a;
    }
  }
#pragma unroll
  for (int m = 0; m < 6; ++m)
    off[((size_t)(b * HW + c) * 18 + (mb + m)) * HW + r] = acc[m];
}

// ---------------------------------------------------------------------------
// Kernel B: gather-coalesced sampling -> LDS fragment staging -> MFMA.
// Block tile: 64 rows (r0..r0+63) x 1 col (c0); 256 threads = 4 waves.
// Phase S (per icb): thread (p=tid&63, q=tid>>6) samples pixel p for planes
//   ic = icb*32 + q*8 + e (e<8) -> each gather instr: 64 lanes, ONE plane,
//   ~contiguous addrs. Packed B-frag written to LDS [n][q][pix][e8].
// Phase M: wave q computes oc-quarter t=q: per n, 1 A-frag global load,
//   4 ds_read_b128 B-frags (pixel groups), 4 MFMAs. acc lives across phases.
// ---------------------------------------------------------------------------
__global__ __launch_bounds__(256) void deform_kernel(
    const float* __restrict__ x, const float* __restrict__ off,
    const short* __restrict__ wf, float* __restrict__ out)
{
  __shared__ short8v sS[9 * 4 * 64];                 // 36,864 B

  const int b   = blockIdx.y;
  const int bx  = blockIdx.x;                        // 4 r-tiles * 256 cols
  const int r0  = (bx & 3) * 64;
  const int c0  = bx >> 2;
  const int tid = threadIdx.x;
  const int p   = tid & 63;                          // pixel within tile
  const int q   = tid >> 6;                          // wave = plane-octet = oc quarter
  const int i   = tid & 15;
  const int hi  = (tid >> 4) & 3;
  const int r   = r0 + p;
  const int c   = c0;

  // ---- fp32-exact corner tables (identical math to R2-verified code) ----
  unsigned qip[9][2];
  float    qg[9][4];
  const float* obp = off + (size_t)(b * HW + c0) * 18 * HW;
#pragma unroll
  for (int n = 0; n < 9; ++n) {
    const float ox = obp[(size_t)n * HW + r];
    const float oy = obp[(size_t)(9 + n) * HW + r];
    // p = p0 + pn + off; transposed base: row coord ~ c, col coord ~ r
    const float px = (float)(c + (n % 3)) + ox;
    const float py = (float)(r + (n / 3)) + oy;
    const float fx = floorf(px);
    const float fy = floorf(py);
    int ltx = (int)fx, lty = (int)fy;
    int rbx = ltx + 1, rby = lty + 1;
    ltx = min(max(ltx, 0), HW + 1); lty = min(max(lty, 0), HW + 1);
    rbx = min(max(rbx, 0), HW + 1); rby = min(max(rby, 0), HW + 1);
    const float pxc = fminf(fmaxf(px, 0.f), (float)(HW + 1));
    const float pyc = fminf(fmaxf(py, 0.f), (float)(HW + 1));
    const float wxl = 1.f + (float)ltx - pxc;
    const float wxr = 1.f - ((float)rbx - pxc);
    const float wyl = 1.f + (float)lty - pyc;
    const float wyr = 1.f - ((float)rby - pyc);
    const int   cx[4] = { ltx, rbx, ltx, rbx };
    const int   cy[4] = { lty, rby, rby, lty };
    const float cg[4] = { wxl * wyl, wxr * wyr, wxl * wyr, wxr * wyl };
    unsigned ii[4];
#pragma unroll
    for (int k = 0; k < 4; ++k) {
      const bool ok = (cx[k] >= 1) & (cx[k] <= HW) & (cy[k] >= 1) & (cy[k] <= HW);
      ii[k]    = ok ? (unsigned)((cx[k] - 1) * HW + (cy[k] - 1)) : 0u;
      qg[n][k] = ok ? cg[k] : 0.f;
    }
    qip[n][0] = ii[0] | (ii[1] << 16);
    qip[n][1] = ii[2] | (ii[3] << 16);
  }

  f32x4 acc[4];
#pragma unroll
  for (int g = 0; g < 4; ++g) acc[g] = (f32x4){0.f, 0.f, 0.f, 0.f};

  const float* xb = x + (size_t)b * CIN * HW2;

  for (int icb = 0; icb < 2; ++icb) {
    // ---------------- Phase S: coalesced sampling into LDS ----------------
    const float* xpl = xb + (size_t)(icb * 32 + q * 8) * HW2;
#pragma unroll
    for (int n = 0; n < 9; ++n) {
      const unsigned p0 = qip[n][0], p1 = qip[n][1];
      const int o0 = (int)(p0 & 0xFFFFu);
      const int o1 = (int)(p0 >> 16);
      const int o2 = (int)(p1 & 0xFFFFu);
      const int o3 = (int)(p1 >> 16);
      const float g0 = qg[n][0], g1 = qg[n][1], g2 = qg[n][2], g3 = qg[n][3];
      short8v sf;
#pragma unroll
      for (int e = 0; e < 8; ++e) {
        const float* xe = xpl + (size_t)e * HW2;
        float sv = g0 * xe[o0];
        sv = fmaf(g1, xe[o1], sv);
        sv = fmaf(g2, xe[o2], sv);
        sv = fmaf(g3, xe[o3], sv);
        sf[e] = (short)f2bf(sv);
      }
      sS[(n * 4 + q) * 64 + p] = sf;
    }
    __syncthreads();

    // ---------------- Phase M: MFMA, wave q handles oc-quarter q ----------
    const short* wfb = wf + ((size_t)(icb * 9) * 4 * 64 + (size_t)q * 64 + p) * 8;
#pragma unroll
    for (int n = 0; n < 9; ++n) {
      const short8v afr = *(const short8v*)(wfb + (size_t)n * 4 * 64 * 8);
#pragma unroll
      for (int g = 0; g < 4; ++g) {
        const short8v bfr = sS[(n * 4 + hi) * 64 + g * 16 + i];
        acc[g] = __builtin_amdgcn_mfma_f32_16x16x32_bf16(afr, bfr, acc[g], 0, 0, 0);
      }
    }
    __syncthreads();
  }

  // C/D layout (R2-verified): col = i = pixel within group, row = hi*4 + j.
#pragma unroll
  for (int g = 0; g < 4; ++g)
#pragma unroll
    for (int j = 0; j < 4; ++j) {
      const int oc = q * 16 + hi * 4 + j;
      out[((size_t)(b * COUT + oc)) * HW2 + (size_t)(r0 + g * 16 + i) * HW + c0]
          = acc[g][j];
    }
}

// ---------------------------------------------------------------------------
extern "C" void kernel_launch(void* const* d_in, const int* in_sizes, int n_in,
                              void* d_out, int out_size, void* d_ws, size_t ws_size,
                              hipStream_t stream) {
  const float* x  = (const float*)d_in[0];   // (2,64,256,256)
  const float* pw = (const float*)d_in[1];   // (18,64,3,3)
  const float* pb = (const float*)d_in[2];   // (18,)
  const float* w  = (const float*)d_in[3];   // (64,64,3,3)
  float* out = (float*)d_out;                // (2,64,256,256)

  float* off = (float*)d_ws;                                   // 9,437,184 B
  short* wfg = (short*)((char*)d_ws + (size_t)2 * 18 * HW2 * 4); // +73,728 B

  wfrag_kernel<<<18, 256, 0, stream>>>(w, wfg);
  dim3 gridA(256, 2, 3);
  offs_kernel<<<gridA, 256, 0, stream>>>(x, pw, pb, off);
  dim3 gridB(1024, 2);
  deform_kernel<<<gridB, 256, 0, stream>>>(x, off, wfg, out);
}